// Round 9
// baseline (61.658 us; speedup 1.0000x reference)
//
#include <hip/hip_runtime.h>
#include <math.h>

#define IMG_H 512
#define IMG_W 512
#define PLANE (IMG_H * IMG_W)
#define NB 9
#define LSTR 264            // [0..2 pad][3]=Lhalo[4..259]=cols 0..255[260]=Rhalo[261..263 pad]
#define BUFSZ (10 * LSTR)   // one band buffer: 10 rows

// Persistent block: 4 vertically-adjacent half-bands, double-buffered LDS gray,
// software-pipelined staging (issue loads for band i+1 before computing band i,
// write them to LDS after band i's reduce). Grid = 32 img x 2 half x 16 groups
// = 1024 blocks of 256 threads; thread t owns local col t of each band.
//
// CORRECTNESS MODEL (do not change): decision chain bit-exact vs the fp32 ref:
//   gray  = ((c0+c1)+c2)/3.0f            (IEEE fp32 div)
//   gx,gy = Sobel, tap-lex order, +-1/+-2 (exact multiplies)
//   fast fp32 atan2 classifier (poly pre-scaled by 9/pi); within 2.5e-4 of
//   integer pb (incl. 0/NaN edges) fall back to exact
//   (float)atan2(fp64) -> /(float)pi*9 -> floored mod 9.
__global__ __launch_bounds__(256, 4) void hog_kernel(const float* __restrict__ x,
                                                     float* __restrict__ out) {
    __shared__ float sgray[2 * BUFSZ];   // 21120 B
    __shared__ float sred[256 * NB];     //  9216 B

    const int t    = threadIdx.x;
    const int n    = blockIdx.x >> 5;
    const int rem  = blockIdx.x & 31;
    const int half = rem >> 4;
    const int cyg  = rem & 15;           // cy = cyg*4 + i
    const int wstart = half * 256;
    const float* xn = x + (size_t)n * 3 * PLANE;

    const int r0   = t >> 6;             // slot rows r0, r0+4, r0+8(if t<128)
    const int c0   = t & 63;
    const int colb = wstart + 4 * c0;

    float4 A0 = make_float4(0,0,0,0), B0 = A0, C0 = A0;
    float4 A1 = A0, B1 = A0, C1 = A0;
    float4 A2 = A0, B2 = A0, C2 = A0;
    float  HA = 0.0f, HB = 0.0f, HC = 0.0f;

// issue global loads for band CY into registers (no wait)
#define ISSUE(CY) {                                                              \
    const int hb_ = (CY) * 8 - 1; int h_; const float* p_;                       \
    h_ = hb_ + r0;                                                               \
    if ((unsigned)h_ < IMG_H) { p_ = xn + (size_t)h_ * IMG_W + colb;             \
        A0 = *(const float4*)p_; B0 = *(const float4*)(p_ + PLANE);              \
        C0 = *(const float4*)(p_ + 2 * PLANE); }                                 \
    h_ = hb_ + r0 + 4;                                                           \
    if ((unsigned)h_ < IMG_H) { p_ = xn + (size_t)h_ * IMG_W + colb;             \
        A1 = *(const float4*)p_; B1 = *(const float4*)(p_ + PLANE);              \
        C1 = *(const float4*)(p_ + 2 * PLANE); }                                 \
    if (t < 128) { h_ = hb_ + r0 + 8;                                            \
        if ((unsigned)h_ < IMG_H) { p_ = xn + (size_t)h_ * IMG_W + colb;         \
            A2 = *(const float4*)p_; B2 = *(const float4*)(p_ + PLANE);          \
            C2 = *(const float4*)(p_ + 2 * PLANE); } }                           \
    if (t < 20) { const int hr_ = t >> 1, sd_ = t & 1; h_ = hb_ + hr_;           \
        const int col_ = wstart - 1 + sd_ * 257;                                 \
        if ((unsigned)h_ < IMG_H && (unsigned)col_ < IMG_W) {                    \
            p_ = xn + (size_t)h_ * IMG_W + col_;                                 \
            HA = p_[0]; HB = p_[PLANE]; HC = p_[2 * PLANE]; } } }

#define GRAY4(A, B, C, V) make_float4(                                           \
    (V) ? ((A.x + B.x) + C.x) / 3.0f : 0.0f,                                     \
    (V) ? ((A.y + B.y) + C.y) / 3.0f : 0.0f,                                     \
    (V) ? ((A.z + B.z) + C.z) / 3.0f : 0.0f,                                     \
    (V) ? ((A.w + B.w) + C.w) / 3.0f : 0.0f)

// convert staged regs to gray and write into LDS buffer BUF for band CY
#define WRITE(BUF, CY) {                                                         \
    const int hb_ = (CY) * 8 - 1; int h_; bool v_; float4 gv_;                   \
    h_ = hb_ + r0; v_ = ((unsigned)h_ < IMG_H); gv_ = GRAY4(A0, B0, C0, v_);     \
    *(float4*)&(BUF)[r0 * LSTR + 4 + 4 * c0] = gv_;                              \
    h_ = hb_ + r0 + 4; v_ = ((unsigned)h_ < IMG_H); gv_ = GRAY4(A1, B1, C1, v_); \
    *(float4*)&(BUF)[(r0 + 4) * LSTR + 4 + 4 * c0] = gv_;                        \
    if (t < 128) { h_ = hb_ + r0 + 8; v_ = ((unsigned)h_ < IMG_H);               \
        gv_ = GRAY4(A2, B2, C2, v_);                                             \
        *(float4*)&(BUF)[(r0 + 8) * LSTR + 4 + 4 * c0] = gv_; }                  \
    if (t < 20) { const int hr_ = t >> 1, sd_ = t & 1; h_ = hb_ + hr_;           \
        const int col_ = wstart - 1 + sd_ * 257;                                 \
        float g_ = 0.0f;                                                         \
        if ((unsigned)h_ < IMG_H && (unsigned)col_ < IMG_W)                      \
            g_ = ((HA + HB) + HC) / 3.0f;                                        \
        (BUF)[hr_ * LSTR + 3 + sd_ * 257] = g_; } }

// classify pixel from window rows (RA,RB,RC); yields L, W0, W1
#define PIXEL(RA, RB, RC, L, W0, W1)                                             \
    {                                                                            \
        const float tl = RA[0], tc = RA[1], tr = RA[2];                          \
        const float ml = RB[0],             mr = RB[2];                          \
        const float bl = RC[0], bc = RC[1], br = RC[2];                          \
        const float gx = ((((tl - tr) + 2.0f * ml) - 2.0f * mr) + bl) - br;      \
        const float gy = ((((tl + 2.0f * tc) + tr) - bl) - 2.0f * bc) - br;      \
        const float nrm = sqrtf(gx * gx + gy * gy);                              \
        const float fa = fabsf(gx), fb = fabsf(gy);                              \
        const float mn = fminf(fa, fb), mx = fmaxf(fa, fb);                      \
        float rcpmx;                                                             \
        asm("v_rcp_f32 %0, %1" : "=v"(rcpmx) : "v"(mx));                         \
        const float tt = mn * rcpmx;                                             \
        const float ss = tt * tt;                                                \
        float po = fmaf(ss, -0.03357890f, 0.15084052f);                          \
        po = fmaf(ss, po, -0.33355581f);                                         \
        po = fmaf(ss, po, 0.55446223f);                                          \
        po = fmaf(ss, po, -0.95289958f);                                         \
        po = fmaf(ss, po, 2.86472384f);     /* poly pre-scaled by 9/pi */        \
        float u = tt * po;                                                       \
        if (fa > fb)    u = 4.5f - u;                                            \
        if (gy < 0.0f)  u = 9.0f - u;                                            \
        if (gx < 0.0f)  u = -u;                                                  \
        const float fl   = floorf(u);                                            \
        const float frac = u - fl;                                               \
        const float dist = fminf(frac, 1.0f - frac);                             \
        if (dist > 2.5e-4f) {               /* NaN -> false -> slow */           \
            int lo = (int)fl; if (lo < 0) lo += NB;                              \
            L = lo; W0 = nrm; W1 = 1.0f - nrm;                                   \
        } else {                                                                 \
            /* exact reference chain (bit-identical to rounds 2-8) */            \
            const float ph  = (float)atan2((double)gx, (double)gy);              \
            const float pbf = ph / (float)M_PI * 9.0f;                           \
            int lo = (int)floorf(pbf) % NB; if (lo < 0) lo += NB;                \
            int hi = (int)ceilf(pbf)  % NB; if (hi < 0) hi += NB;                \
            L = lo;                                                              \
            if (lo == hi) { W0 = nrm + (1.0f - nrm); W1 = 0.0f; }                \
            else          { W0 = nrm; W1 = 1.0f - nrm; }                         \
        }                                                                        \
    }

    // ---- prologue: stage band cyg*4 into buffer 0 ----
    ISSUE(cyg * 4)
    WRITE(sgray, cyg * 4)
    __syncthreads();

    for (int i = 0; i < 4; ++i) {
        const int cy = cyg * 4 + i;
        float* buf = &sgray[(i & 1) * BUFSZ];

        if (i < 3) ISSUE(cy + 1)   // loads in flight during compute

        float bins[NB];
#pragma unroll
        for (int b = 0; b < NB; b++) bins[b] = 0.0f;

        // two rolling windows: chain A = rows 0..3, chain B = rows 4..7
        float raA[3], rbA[3], rcA[3], raB[3], rbB[3], rcB[3];
        {
            const float* p0 = buf + 0 * LSTR + t;
            const float* p1 = buf + 1 * LSTR + t;
            const float* p4 = buf + 4 * LSTR + t;
            const float* p5 = buf + 5 * LSTR + t;
            raA[0] = p0[3]; raA[1] = p0[4]; raA[2] = p0[5];
            rbA[0] = p1[3]; rbA[1] = p1[4]; rbA[2] = p1[5];
            raB[0] = p4[3]; raB[1] = p4[4]; raB[2] = p4[5];
            rbB[0] = p5[3]; rbB[1] = p5[4]; rbB[2] = p5[5];
        }

#pragma unroll
        for (int k = 0; k < 4; k++) {
            const float* pA = buf + (k + 2) * LSTR + t;
            const float* pB = buf + (k + 6) * LSTR + t;
            rcA[0] = pA[3]; rcA[1] = pA[4]; rcA[2] = pA[5];
            rcB[0] = pB[3]; rcB[1] = pB[4]; rcB[2] = pB[5];

            int lA, lB; float w0A, w1A, w0B, w1B;
            PIXEL(raA, rbA, rcA, lA, w0A, w1A)
            PIXEL(raB, rbB, rcB, lB, w0B, w1B)

            bool mA[NB], mB[NB];
#pragma unroll
            for (int b = 0; b < NB; b++) { mA[b] = (lA == b); mB[b] = (lB == b); }
#pragma unroll
            for (int b = 0; b < NB; b++) {
                const int bp = (b + 8) % 9;
                bins[b] += (mA[b] ? w0A : (mA[bp] ? w1A : 0.0f))
                         + (mB[b] ? w0B : (mB[bp] ? w1B : 0.0f));
            }

#pragma unroll
            for (int q = 0; q < 3; q++) {
                raA[q] = rbA[q]; rbA[q] = rcA[q];
                raB[q] = rbB[q]; rbB[q] = rcB[q];
            }
        }

#pragma unroll
        for (int b = 0; b < NB; b++) sred[t * NB + b] = bins[b];
        __syncthreads();

        // cell cc (local cols 8cc..8cc+7) gathers threads 8cc..8cc+7
        for (int idx = t; idx < NB * 32; idx += 256) {
            const int b  = idx >> 5;
            const int cc = idx & 31;
            const int base = 8 * cc * NB + b;
            float s = sred[base];
#pragma unroll
            for (int j = 1; j < 8; j++) s += sred[base + j * NB];
            out[((size_t)n * NB + b) * 4096 + (size_t)cy * 64 + half * 32 + cc]
                = s * (1.0f / 64.0f);
        }

        if (i < 3) WRITE(&sgray[((i + 1) & 1) * BUFSZ], cy + 1)
        __syncthreads();
    }
#undef PIXEL
#undef WRITE
#undef GRAY4
#undef ISSUE
}

extern "C" void kernel_launch(void* const* d_in, const int* in_sizes, int n_in,
                              void* d_out, int out_size, void* d_ws, size_t ws_size,
                              hipStream_t stream) {
    const float* x = (const float*)d_in[0];
    float* out = (float*)d_out;
    // 32 images x 2 halves x 16 band-groups = 1024 blocks of 256
    hog_kernel<<<1024, 256, 0, stream>>>(x, out);
}